// Round 12
// baseline (288.589 us; speedup 1.0000x reference)
//
#include <hip/hip_runtime.h>
#include <hip/hip_bf16.h>

#define DD 1024
#define NB 16384
#define SZ (DD * DD)
#define CHB 256

typedef unsigned short u16;
typedef __attribute__((ext_vector_type(2))) float f32x2;
typedef __attribute__((ext_vector_type(4))) float f32x4;
typedef __attribute__((ext_vector_type(16))) float f32x16;
typedef __attribute__((ext_vector_type(8))) short short8;
typedef __attribute__((ext_vector_type(4))) short short4v;

__device__ __forceinline__ u16 f32_bf16(float f) {
  unsigned u = __builtin_bit_cast(unsigned, f);
  u += 0x7FFFu + ((u >> 16) & 1u);   // RNE
  return (u16)(u >> 16);
}
__device__ __forceinline__ float bf16_f32(u16 h) {
  unsigned u = ((unsigned)h) << 16;
  return __builtin_bit_cast(float, u);
}
__device__ __forceinline__ void gload16(const void* g, void* l) {
  __builtin_amdgcn_global_load_lds(
      (const __attribute__((address_space(1))) unsigned int*)g,
      (__attribute__((address_space(3))) unsigned int*)l, 16, 0, 0);
}

// ---------------------------------------------------------------- chain GEMM
// Complex bf16 GEMM, BM=64 BN=64 BK=32, 256 thr (4 waves 2x2).
// PAIRED-SLOT schedule with HOISTED READS (r10, 282us state).  FROZEN.
// Blocks >= CHB do f32->bf16 x-conversion into dead workspace planes.
// NOTE (r8): do NOT mega-fuse the chain cooperatively (rule #20 + grid.sync).
struct CArgs {
  const u16 *Ar[3], *Ai[3];      // A planes [M][K]
  const u16 *Br[3], *Bi[3];      // B^T planes [N][K]
  int nseg;
  float alpha, g1, g2, ddiag;
  const u16 *e1r, *e1i, *e2r, *e2i;
  u16 *hi_n_re, *hi_n_im, *lo_n_re, *lo_n_im;   // normal outs (ld DD)
  u16 *t1_re, *t1_im;            // transposed hi outs
  u16 *t2_re, *t2_im;            // second transposed hi pair (packs)
  u16 *lt_re, *lt_im;            // transposed lo outs
  int t_ldt;                     // ld for transposed outs
  unsigned t1_xi;                // sign mask for t1 im (0x8000 => negate)
  const float *cxr, *cxi; u16 *cxb;
  int cm0a, cm1a, cm0b, cm1b;    // conversion row ranges
};

__global__ __launch_bounds__(256, 2) void zchain(CArgs g) {
  constexpr int SA = 64 * 32, SB = 64 * 32;      // u16 per plane
  constexpr int SLOT = 2 * SA + 2 * SB;          // 8192 u16 = 16 KB
  __shared__ __align__(16) u16 smem[4 * SLOT];   // 64 KB
  const int tid = threadIdx.x;

  if ((int)blockIdx.x >= CHB) {                  // -------- conversion blocks
    int nra = g.cm1a - g.cm0a;
    int tot = nra + (g.cm1b - g.cm0b);
    for (int r = (int)blockIdx.x - CHB; r < tot; r += 256) {
      int m = (r < nra) ? (g.cm0a + r) : (g.cm0b + r - nra);
      f32x4 v = ((const f32x4*)g.cxr)[m * 256 + tid];
      short4v s;
      #pragma unroll
      for (int e = 0; e < 4; ++e) s[e] = (short)f32_bf16(v[e]);
      ((short4v*)g.cxb)[m * 512 + tid] = s;
      f32x4 w = ((const f32x4*)g.cxi)[m * 256 + tid];
      #pragma unroll
      for (int e = 0; e < 4; ++e) s[e] = (short)f32_bf16(w[e]);
      ((short4v*)g.cxb)[m * 512 + 256 + tid] = s;
    }
    return;
  }

  const int lane = tid & 63, wave = tid >> 6;
  const int wr = wave >> 1, wc = wave & 1;
  const int l15 = lane & 15, lg = lane >> 4;

  // XCD swizzle: each XCD owns a 4x8 (by,bx) region of the 16x16 grid
  const int lin = blockIdx.x;
  const int xcd = lin & 7, tt = lin >> 3;        // tt in [0,32)
  const int by = (xcd >> 1) * 4 + (tt >> 3);
  const int bx = (xcd & 1) * 8 + (tt & 7);
  const int m0 = by * 64, n0 = bx * 64;

  // staging maps; granule swizzle q^((row>>1)&3) (conflict-free, matches
  // read-side slotR since (row>>1)&3 == (l15>>1)&3)
  const int arow = tid >> 2, agc = tid & 3;
  const int offA = (m0 + arow) * DD + ((agc ^ ((arow >> 1) & 3)) * 8);
  const int offB = (n0 + arow) * DD + ((agc ^ ((arow >> 1) & 3)) * 8);
  const int ldsAB = tid * 8;                     // lane-contiguous 16B

  const int slotR = lg ^ ((l15 >> 1) & 3);
  int frA[2], frB[2];
  #pragma unroll
  for (int mf = 0; mf < 2; ++mf)
    frA[mf] = (wr * 32 + mf * 16 + l15) * 32 + slotR * 8;
  #pragma unroll
  for (int nf = 0; nf < 2; ++nf)
    frB[nf] = (wc * 32 + nf * 16 + l15) * 32 + slotR * 8;

  const int nt = g.nseg * 32;                    // even (>=32)

  auto ISSUE = [&](int b) {
    if (b >= nt) return;
    int s = b >> 5, kk = (b & 31) << 5;
    u16* base = smem + (b & 3) * SLOT;
    gload16(g.Ar[s] + offA + kk, base + ldsAB);
    gload16(g.Ai[s] + offA + kk, base + SA + ldsAB);
    gload16(g.Br[s] + offB + kk, base + 2 * SA + ldsAB);
    gload16(g.Bi[s] + offB + kk, base + 2 * SA + SB + ldsAB);
  };

  f32x4 accre[2][2] = {};
  f32x4 accim[2][2] = {};

  // prologue: pair 0 only; expose latency once
  ISSUE(0); ISSUE(1);
  asm volatile("s_waitcnt vmcnt(0)" ::: "memory");
  __builtin_amdgcn_s_barrier();

  for (int b = 0; b < nt; b += 2) {
    // stage pair b+2 -> other half (consumed last iteration; barrier passed)
    ISSUE(b + 2); ISSUE(b + 3);

    // ---- hoisted reads: ALL 16 fragments of the pair upfront (both slots
    // resident; lets the compiler hide ds_read latency under first MFMAs)
    short8 ar[2][2], ai[2][2], br[2][2], bi[2][2];
    #pragma unroll
    for (int h2 = 0; h2 < 2; ++h2) {
      const u16* base = smem + ((b + h2) & 3) * SLOT;
      #pragma unroll
      for (int mf = 0; mf < 2; ++mf) {
        ar[h2][mf] = *(const short8*)(base + frA[mf]);
        ai[h2][mf] = *(const short8*)(base + SA + frA[mf]);
      }
      #pragma unroll
      for (int nf = 0; nf < 2; ++nf) {
        br[h2][nf] = *(const short8*)(base + 2 * SA + frB[nf]);
        bi[h2][nf] = *(const short8*)(base + 2 * SA + SB + frB[nf]);
      }
    }

    #pragma unroll
    for (int h2 = 0; h2 < 2; ++h2) {
      short8 bin[2];
      #pragma unroll
      for (int nf = 0; nf < 2; ++nf)
        #pragma unroll
        for (int e = 0; e < 8; ++e)
          bin[nf][e] = (short)(bi[h2][nf][e] ^ (short)0x8000);
      #pragma unroll
      for (int mf = 0; mf < 2; ++mf)
      #pragma unroll
      for (int nf = 0; nf < 2; ++nf) {
        accre[mf][nf] = __builtin_amdgcn_mfma_f32_16x16x32_bf16(ar[h2][mf], br[h2][nf],  accre[mf][nf], 0, 0, 0);
        accre[mf][nf] = __builtin_amdgcn_mfma_f32_16x16x32_bf16(ai[h2][mf], bin[nf],     accre[mf][nf], 0, 0, 0);
        accim[mf][nf] = __builtin_amdgcn_mfma_f32_16x16x32_bf16(ar[h2][mf], bi[h2][nf],  accim[mf][nf], 0, 0, 0);
        accim[mf][nf] = __builtin_amdgcn_mfma_f32_16x16x32_bf16(ai[h2][mf], br[h2][nf],  accim[mf][nf], 0, 0, 0);
      }
    }

    if (b + 2 < nt) {
      asm volatile("s_waitcnt vmcnt(0)" ::: "memory");   // pair b+2 landed
      __builtin_amdgcn_s_barrier();
    }
  }

  // ---- epilogue
  u16 hre[2][2][4], hie[2][2][4], lre[2][2][4], lie[2][2][4];
  #pragma unroll
  for (int mf = 0; mf < 2; ++mf)
  #pragma unroll
  for (int nf = 0; nf < 2; ++nf)
  #pragma unroll
  for (int r = 0; r < 4; ++r) {
    int gr = m0 + wr * 32 + mf * 16 + lg * 4 + r;
    int gc = n0 + wc * 32 + nf * 16 + l15;
    size_t idx = (size_t)gr * DD + gc;
    float v = g.alpha * accre[mf][nf][r];
    float w = g.alpha * accim[mf][nf][r];
    if (g.e1r) { v += g.g1 * bf16_f32(g.e1r[idx]); w += g.g1 * bf16_f32(g.e1i[idx]); }
    if (g.e2r) { v += g.g2 * bf16_f32(g.e2r[idx]); w += g.g2 * bf16_f32(g.e2i[idx]); }
    if (gr == gc) v += g.ddiag;
    u16 h1 = f32_bf16(v); hre[mf][nf][r] = h1;
    u16 h2 = f32_bf16(w); hie[mf][nf][r] = h2;
    lre[mf][nf][r] = f32_bf16(v - bf16_f32(h1));
    lie[mf][nf][r] = f32_bf16(w - bf16_f32(h2));
    if (g.hi_n_re) { g.hi_n_re[idx] = h1; g.hi_n_im[idx] = h2; }
    if (g.lo_n_re) { g.lo_n_re[idx] = lre[mf][nf][r]; g.lo_n_im[idx] = lie[mf][nf][r]; }
  }

  auto bounce = [&](u16 (&vals)[2][2][4], u16* outp, unsigned xorm) {
    if (!outp) return;
    __syncthreads();
    #pragma unroll
    for (int mf = 0; mf < 2; ++mf)
    #pragma unroll
    for (int nf = 0; nf < 2; ++nf)
    #pragma unroll
    for (int r = 0; r < 4; ++r) {
      int row = wr * 32 + mf * 16 + lg * 4 + r;
      int col = wc * 32 + nf * 16 + l15;
      smem[row * 66 + col] = vals[mf][nf][r];
    }
    __syncthreads();
    {
      int col = tid & 63, mb = (tid >> 6) * 16;
      short8 s0, s1;
      #pragma unroll
      for (int j = 0; j < 8; ++j) s0[j] = (short)(smem[(mb + j) * 66 + col] ^ xorm);
      #pragma unroll
      for (int j = 0; j < 8; ++j) s1[j] = (short)(smem[(mb + 8 + j) * 66 + col] ^ xorm);
      u16* p = outp + (size_t)(n0 + col) * g.t_ldt + m0 + mb;
      *(short8*)p = s0; *(short8*)(p + 8) = s1;
    }
  };

  bounce(hre, g.t1_re, 0);
  bounce(hie, g.t1_im, g.t1_xi);
  bounce(hre, g.t2_re, 0);
  bounce(hie, g.t2_im, 0);
  bounce(lre, g.lt_re, 0);
  bounce(lie, g.lt_im, 0);
}

// ---------------------------------------------------------------- big GEMM
// Real bf16 GEMM, 8-phase quadrant schedule, 32x32x16 MFMA (r12).
// r11 lesson (counter-backed): [pos][64] rows = 128B stride => bank phase
// loses row contribution => 6.29M LDS conflicts.  Fix: each K=64 operand
// half stored as TWO K=32 sub-regions [2 region][128 pos][4 chunk][8 u16]
// (64B row stride — same bank geometry as the proven conflict-free 16x16
// layout).  Staging stays linear (c -> region=c>>9, pos=(c>>2)&127,
// chunk=c&3; global granule G = region*4 + (chunk ^ ((pos>>1)&3))); reads
// use region=G>>2, chunk=(G&3)^((pos>>1)&3).  Round-trip verified.
// MFMA order identical to r11 (refcheck'd, absmax 0.03125).
#define RG_SLOT2 (2 * 256 * 64)          // 32768 u16 = 64 KB per buffer
#define RG_LDS_BYTES (2 * RG_SLOT2 * 2)  // 128 KB
#define RG_TILES 32                      // K = 2048 / 64

__global__ __launch_bounds__(512, 2) void rgemm(
    const u16* __restrict__ A, const u16* __restrict__ B,
    float* __restrict__ out, int ostride, int ooff)
{
  extern __shared__ u16 smem[];
  const int tid = threadIdx.x, lane = tid & 63, wave = tid >> 6;
  const int wr = wave >> 2, wc = wave & 3;
  const int l31 = lane & 31, kg = lane >> 5;

  int bx, by;
  { int lin = blockIdx.y * gridDim.x + blockIdx.x;   // grid (4, 64) = 256
    int orig = (lin & 7) * 32 + (lin >> 3);
    bx = orig & 3; by = orig >> 2; }
  const int m0 = by * 256, n0 = bx * 256;

  const u16* __restrict__ Abase = A + (size_t)m0 * 2048;
  const u16* __restrict__ Bbase = B + (size_t)n0 * 2048;

  // staging: c -> (region, pos, chunk); global k-granule pre-swizzled so the
  // read-side XOR recovers it.  LDS dest stays linear (c*16B).
  int gofsA[2], gofsB[2], lofs[2];
  #pragma unroll
  for (int i = 0; i < 2; ++i) {
    int c = i * 512 + tid;
    int region = c >> 9;                  // 0..1 (K=32 sub-region)
    int pos = (c >> 2) & 127;
    int chunk = c & 3;
    int G = region * 4 + (chunk ^ ((pos >> 1) & 3));
    int rowA = (pos & 63) + 128 * (pos >> 6);
    int rowB = (pos & 31) + 64 * (pos >> 5);
    gofsA[i] = rowA * 2048 + G * 8;
    gofsB[i] = rowB * 2048 + G * 8;
    lofs[i] = c * 8;
  }

  // frag read offsets (u16 within half-region; +8192 for hi half):
  // offset = (G>>2)*4096 + pos*32 + ((G&3)^((l31>>1)&3))*8, G = k2*2+kg
  int raf[2][4], rbf[4];
  #pragma unroll
  for (int mh = 0; mh < 2; ++mh)
    #pragma unroll
    for (int k2 = 0; k2 < 4; ++k2) {
      int G = k2 * 2 + kg;
      raf[mh][k2] = (G >> 2) * 4096 + (wr * 64 + mh * 32 + l31) * 32 +
                    (((G & 3) ^ ((l31 >> 1) & 3)) * 8);
    }
  #pragma unroll
  for (int k2 = 0; k2 < 4; ++k2) {
    int G = k2 * 2 + kg;
    rbf[k2] = (G >> 2) * 4096 + (wc * 32 + l31) * 32 +
              (((G & 3) ^ ((l31 >> 1) & 3)) * 8);
  }

  f32x16 acc[4][2] = {};
  short8 aF[2][4], bbl[4], bbh[4];

#define MFMA_Q32(mtb, BB)                                                     \
  _Pragma("unroll")                                                           \
  for (int mh = 0; mh < 2; ++mh)                                              \
    _Pragma("unroll")                                                         \
    for (int k2 = 0; k2 < 4; ++k2)                                            \
      acc[(mtb) + mh][(&BB == &bbh) ? 1 : 0] =                                \
          __builtin_amdgcn_mfma_f32_32x32x16_bf16(                            \
              aF[mh][k2], BB[k2], acc[(mtb) + mh][(&BB == &bbh) ? 1 : 0], 0, 0, 0);

  {
    gload16(Abase + gofsA[0], smem + lofs[0]);
    gload16(Abase + gofsA[1], smem + lofs[1]);
    gload16(Bbase + gofsB[0], smem + 16384 + lofs[0]);
    gload16(Bbase + gofsB[1], smem + 16384 + lofs[1]);
    gload16(Bbase + gofsB[0] + 32 * 2048, smem + 16384 + 8192 + lofs[0]);
    gload16(Bbase + gofsB[1] + 32 * 2048, smem + 16384 + 8192 + lofs[1]);
    gload16(Abase + gofsA[0] + 64 * 2048, smem + 8192 + lofs[0]);
    gload16(Abase + gofsA[1] + 64 * 2048, smem + 8192 + lofs[1]);
    gload16(Abase + gofsA[0] + 64, smem + RG_SLOT2 + lofs[0]);
    gload16(Abase + gofsA[1] + 64, smem + RG_SLOT2 + lofs[1]);
    gload16(Bbase + gofsB[0] + 64, smem + RG_SLOT2 + 16384 + lofs[0]);
    gload16(Bbase + gofsB[1] + 64, smem + RG_SLOT2 + 16384 + lofs[1]);
  }
  asm volatile("s_waitcnt vmcnt(4)" ::: "memory");
  __builtin_amdgcn_s_barrier();

  auto TILE = [&](int t, int gate, bool st01, bool st23) {
    const int b = t & 1;
    const u16* bA = smem + b * RG_SLOT2;
    const u16* bB = bA + 16384;
    u16* sOpp  = smem + (b ^ 1) * RG_SLOT2;
    u16* sSame = smem + b * RG_SLOT2;
    // ---- p0: read A-lo(8) + B-lo(4); stage B-hi(t+1); MFMA mt{0,1} x ntl0
    #pragma unroll
    for (int mh = 0; mh < 2; ++mh)
      #pragma unroll
      for (int k2 = 0; k2 < 4; ++k2)
        aF[mh][k2] = *(const short8*)(bA + raf[mh][k2]);
    #pragma unroll
    for (int k2 = 0; k2 < 4; ++k2) bbl[k2] = *(const short8*)(bB + rbf[k2]);
    if (st01) {
      int kk = (t + 1) * 64;
      gload16(Bbase + gofsB[0] + 32 * 2048 + kk, sOpp + 16384 + 8192 + lofs[0]);
      gload16(Bbase + gofsB[1] + 32 * 2048 + kk, sOpp + 16384 + 8192 + lofs[1]);
    }
    asm volatile("s_waitcnt lgkmcnt(8)" ::: "memory");
    __builtin_amdgcn_s_barrier();
    asm volatile("s_waitcnt lgkmcnt(0)" ::: "memory");
    __builtin_amdgcn_sched_barrier(0);
    __builtin_amdgcn_s_setprio(1);
    MFMA_Q32(0, bbl);
    __builtin_amdgcn_s_setprio(0);
    __builtin_amdgcn_s_barrier();
    // ---- p1: read B-hi(4); stage A-hi(t+1); MFMA mt{0,1} x ntl1
    #pragma unroll
    for (int k2 = 0; k2 < 4; ++k2) bbh[k2] = *(const short8*)(bB + 8192 + rbf[k2]);
    if (st01) {
      int kk = (t + 1) * 64;
      gload16(Abase + gofsA[0] + 64 * 2048 + kk, sOpp + 8192 + lofs[0]);
      gload16(Abase + gofsA[1] + 64 * 2048 + kk, sOpp + 8192 + lofs[1]);
    }
    __builtin_amdgcn_s_barrier();
    asm volatile("s_waitcnt lgkmcnt(0)" ::: "memory");
    __builtin_amdgcn_sched_barrier(0);
    __builtin_amdgcn_s_setprio(1);
    MFMA_Q32(0, bbh);
    __builtin_amdgcn_s_setprio(0);
    __builtin_amdgcn_s_barrier();
    // ---- p2: read A-hi(8); stage A-lo(t+2); MFMA mt{2,3} x ntl0
    #pragma unroll
    for (int mh = 0; mh < 2; ++mh)
      #pragma unroll
      for (int k2 = 0; k2 < 4; ++k2)
        aF[mh][k2] = *(const short8*)(bA + 8192 + raf[mh][k2]);
    if (st23) {
      int kk = (t + 2) * 64;
      gload16(Abase + gofsA[0] + kk, sSame + lofs[0]);
      gload16(Abase + gofsA[1] + kk, sSame + lofs[1]);
    }
    __builtin_amdgcn_s_barrier();
    asm volatile("s_waitcnt lgkmcnt(0)" ::: "memory");
    __builtin_amdgcn_sched_barrier(0);
    __builtin_amdgcn_s_setprio(1);
    MFMA_Q32(2, bbl);
    __builtin_amdgcn_s_setprio(0);
    __builtin_amdgcn_s_barrier();
    // ---- p3: stage B-lo(t+2); MFMA mt{2,3} x ntl1; tile-boundary gate
    if (st23) {
      int kk = (t + 2) * 64;
      gload16(Bbase + gofsB[0] + kk, sSame + 16384 + lofs[0]);
      gload16(Bbase + gofsB[1] + kk, sSame + 16384 + lofs[1]);
    }
    __builtin_amdgcn_s_barrier();
    __builtin_amdgcn_sched_barrier(0);
    __builtin_amdgcn_s_setprio(1);
    MFMA_Q32(2, bbh);
    __builtin_amdgcn_s_setprio(0);
    if (gate == 4)      asm volatile("s_waitcnt vmcnt(4)" ::: "memory");
    else if (gate == 0) asm volatile("s_waitcnt vmcnt(0)" ::: "memory");
    if (gate >= 0) __builtin_amdgcn_s_barrier();
  };

  for (int t = 0; t < RG_TILES - 2; ++t) TILE(t, 4, true, true);
  TILE(RG_TILES - 2, 0, true, false);
  TILE(RG_TILES - 1, -1, false, false);
#undef MFMA_Q32

  // C/D layout (m74/m101): col = lane&31, row = (reg&3)+8*(reg>>2)+4*kg
  #pragma unroll
  for (int mt = 0; mt < 4; ++mt)
  #pragma unroll
  for (int ntl = 0; ntl < 2; ++ntl)
  #pragma unroll
  for (int reg = 0; reg < 16; ++reg) {
    int gr = m0 + wr * 128 + mt * 32 + (reg & 3) + 8 * (reg >> 2) + 4 * kg;
    int gc = n0 + wc * 64 + ntl * 32 + l31;
    out[((size_t)gr * DD + gc) * ostride + ooff] = acc[mt][ntl][reg];
  }
}

// ---------------------------------------------------------------- prep
__global__ __launch_bounds__(256) void prep_w(
    const float* __restrict__ wre, const float* __restrict__ wim,
    u16* Shr, u16* Shi_, u16* Slr, u16* Sli, u16* Snr)
{
  __shared__ float tr[32][33], ti[32][33];
  const int tx = threadIdx.x, ty = threadIdx.y;
  const int bx = blockIdx.x, by = blockIdx.y;
  #pragma unroll
  for (int k = 0; k < 4; ++k) {
    int r = bx * 32 + ty + 8 * k, c = by * 32 + tx;
    tr[ty + 8 * k][tx] = wre[r * DD + c];
    ti[ty + 8 * k][tx] = wim[r * DD + c];
  }
  __syncthreads();
  #pragma unroll
  for (int k = 0; k < 4; ++k) {
    int i = by * 32 + ty + 8 * k, j = bx * 32 + tx;
    float wr_ij = wre[i * DD + j], wi_ij = wim[i * DD + j];
    float wr_ji = tr[tx][ty + 8 * k], wi_ji = ti[tx][ty + 8 * k];
    float Sre = wr_ji - wr_ij;
    float Sim = wi_ij + wi_ji;
    int idx = i * DD + j;
    u16 h1 = f32_bf16(Sre); Shr[idx] = h1; Slr[idx] = f32_bf16(Sre - bf16_f32(h1));
    u16 h2 = f32_bf16(Sim); Shi_[idx] = h2; Sli[idx] = f32_bf16(Sim - bf16_f32(h2));
    Snr[idx] = (u16)(h1 ^ 0x8000u);
  }
}

__global__ __launch_bounds__(256) void prep_x2(
    const float* __restrict__ xr, const float* __restrict__ xi,
    u16* __restrict__ xb, int m0a, int m1a, int m0b, int m1b)
{
  int nra = m1a - m0a;
  int tot = nra + (m1b - m0b);
  const int tid = threadIdx.x;
  for (int r = blockIdx.x; r < tot; r += gridDim.x) {
    int m = (r < nra) ? (m0a + r) : (m0b + r - nra);
    f32x4 v = ((const f32x4*)xr)[m * 256 + tid];
    short4v s;
    #pragma unroll
    for (int e = 0; e < 4; ++e) s[e] = (short)f32_bf16(v[e]);
    ((short4v*)xb)[m * 512 + tid] = s;
    f32x4 w = ((const f32x4*)xi)[m * 256 + tid];
    #pragma unroll
    for (int e = 0; e < 4; ++e) s[e] = (short)f32_bf16(w[e]);
    ((short4v*)xb)[m * 512 + 256 + tid] = s;
  }
}

// ---------------------------------------------------------------- launcher
extern "C" void kernel_launch(void* const* d_in, const int* in_sizes, int n_in,
                              void* d_out, int out_size, void* d_ws, size_t ws_size,
                              hipStream_t stream)
{
  const float* xr  = (const float*)d_in[0];
  const float* xi  = (const float*)d_in[1];
  const float* wre = (const float*)d_in[2];
  const float* wim = (const float*)d_in[3];
  const bool realOut = (out_size == NB * DD);

  u16* P0 = (u16*)d_ws;
  auto PL = [&](int k) { return P0 + (size_t)k * SZ; };
  // plane map (peak 35 planes real path; 37 in complex fallback):
  u16 *Shr = PL(0), *Shi_ = PL(1), *Slr = PL(2), *Sli = PL(3), *Snr = PL(4);
  u16 *Cn_r = PL(5), *Cn_i = PL(6), *Ct_r = PL(7), *Ct_i = PL(8);
  u16 *Rn_r = PL(9), *Rn_i = PL(10);
  u16 *XA_hn_r = PL(11), *XA_hn_i = PL(12), *XA_ht_r = PL(13), *XA_ht_i = PL(14);
  u16 *XB_hn_r = PL(19), *XB_hn_i = PL(20), *XB_ht_r = PL(21), *XB_ht_i = PL(22);
  u16 *XB_ln_r = PL(23), *XB_ln_i = PL(24), *XB_lt_r = PL(25), *XB_lt_i = PL(26);
  u16 *T_ht_r = PL(29), *T_ht_i = PL(30), *T_lt_r = PL(31), *T_lt_i = PL(32);
  u16 *pack1 = PL(33);           // [1024][2048]
  u16 *pack2 = PL(35);           // complex path
  u16 *xb    = PL(0);            // [16384][2048] bf16, planes 0-31

  dim3 blk(256);
  prep_w<<<dim3(32, 32), dim3(32, 8), 0, stream>>>(
      wre, wim, Shr, Shi_, Slr, Sli, Snr);

  auto chain = [&](CArgs& a, int p0, int p1, int p0b, int p1b) {
    a.cxr = xr; a.cxi = xi; a.cxb = xb;
    a.cm0a = p0 * 512; a.cm1a = p1 * 512;
    a.cm0b = p0b * 512; a.cm1b = p1b * 512;
    zchain<<<dim3(CHB + 256), blk, 0, stream>>>(a);
  };
  auto base = [&]() { CArgs a{}; a.nseg = 1; a.t_ldt = DD; return a; };

  // deg-3 Chebyshev seed on s = 1+lambda^2 in [1, 7.8] (rho0 = 0.2089):
  //   R = 0.7910964 I + 0.2381155 C + 0.0212604 C^2,  C = S^2
  // G1: C = S*S
  { CArgs a = base();
    a.Ar[0] = Shr; a.Ai[0] = Shi_; a.Br[0] = Snr; a.Bi[0] = Shi_;
    a.alpha = 1.f;
    a.hi_n_re = Cn_r; a.hi_n_im = Cn_i; a.t1_re = Ct_r; a.t1_im = Ct_i;
    chain(a, 15, 19, 0, 0); }
  // G2: R = q2*(C*C) + q1*C + q0*I
  { CArgs a = base();
    a.Ar[0] = Cn_r; a.Ai[0] = Cn_i; a.Br[0] = Ct_r; a.Bi[0] = Ct_i;
    a.alpha = 0.0212604f; a.g1 = 0.2381155f; a.e1r = Cn_r; a.e1i = Cn_i;
    a.ddiag = 0.7910964f;
    a.hi_n_re = Rn_r; a.hi_n_im = Rn_i;
    chain(a, 27, 29, 0, 0); }
  // G3: X0 = R*S + R
  { CArgs a = base();
    a.Ar[0] = Rn_r; a.Ai[0] = Rn_i; a.Br[0] = Snr; a.Bi[0] = Shi_;
    a.alpha = 1.f; a.g1 = 1.f; a.e1r = Rn_r; a.e1i = Rn_i;
    a.hi_n_re = XA_hn_r; a.hi_n_im = XA_hn_i; a.t1_re = XA_ht_r; a.t1_im = XA_ht_i;
    chain(a, 0, 0, 0, 0); }
  // quadratic NS: T = X0 - S*X0  (transposed out only)
  { CArgs a = base();
    a.Ar[0] = Shr; a.Ai[0] = Shi_; a.Br[0] = XA_ht_r; a.Bi[0] = XA_ht_i;
    a.alpha = -1.f; a.g1 = 1.f; a.e1r = XA_hn_r; a.e1i = XA_hn_i;
    a.t1_re = T_ht_r; a.t1_im = T_ht_i;
    chain(a, 4, 8, 0, 0); }
  // X1 = 2*X0 - X0*T   (hi+lo, normal+transposed)
  { CArgs a = base();
    a.Ar[0] = XA_hn_r; a.Ai[0] = XA_hn_i; a.Br[0] = T_ht_r; a.Bi[0] = T_ht_i;
    a.alpha = -1.f; a.g1 = 2.f; a.e1r = XA_hn_r; a.e1i = XA_hn_i;
    a.hi_n_re = XB_hn_r; a.hi_n_im = XB_hn_i; a.t1_re = XB_ht_r; a.t1_im = XB_ht_i;
    a.lo_n_re = XB_ln_r; a.lo_n_im = XB_ln_i; a.lt_re = XB_lt_r; a.lt_im = XB_lt_i;
    chain(a, 8, 11, 0, 0); }
  // polish-1 (split): T' = X - S*X,  S*X ~ Sh*Xh + Sh*Xl + Sl*Xh
  { CArgs a = base();
    a.nseg = 3;
    a.Ar[0] = Shr; a.Ai[0] = Shi_; a.Br[0] = XB_ht_r; a.Bi[0] = XB_ht_i;
    a.Ar[1] = Shr; a.Ai[1] = Shi_; a.Br[1] = XB_lt_r; a.Bi[1] = XB_lt_i;
    a.Ar[2] = Slr; a.Ai[2] = Sli;  a.Br[2] = XB_ht_r; a.Bi[2] = XB_ht_i;
    a.alpha = -1.f;
    a.g1 = 1.f; a.e1r = XB_hn_r; a.e1i = XB_hn_i;
    a.g2 = 1.f; a.e2r = XB_ln_r; a.e2i = XB_ln_i;
    a.t1_re = T_ht_r; a.t1_im = T_ht_i; a.lt_re = T_lt_r; a.lt_im = T_lt_i;
    chain(a, 11, 15, 0, 0); }
  // polish-2 + H-fold: H = -2(Xh*T'h + Xh*T'l) + 4Xh + 2Xl - I  (= U^T)
  // pack1 = [Hr^T | -Hi^T]; pack2 = [Hi^T | Hr^T] (complex path)
  { CArgs a = base();
    a.nseg = 2;
    a.Ar[0] = XB_hn_r; a.Ai[0] = XB_hn_i; a.Br[0] = T_ht_r; a.Bi[0] = T_ht_i;
    a.Ar[1] = XB_hn_r; a.Ai[1] = XB_hn_i; a.Br[1] = T_lt_r; a.Bi[1] = T_lt_i;
    a.alpha = -2.f;
    a.g1 = 4.f; a.e1r = XB_hn_r; a.e1i = XB_hn_i;
    a.g2 = 2.f; a.e2r = XB_ln_r; a.e2i = XB_ln_i;
    a.ddiag = -1.f;
    a.t_ldt = 2048;
    a.t1_re = pack1; a.t1_im = pack1 + 1024; a.t1_xi = 0x8000u;
    if (!realOut) { a.t2_im = pack2; a.t2_re = pack2 + 1024; }
    chain(a, 0, 4, 0, 0); }

  // remaining xb planes: [19,27) and [29,32)
  prep_x2<<<dim3(1024), blk, 0, stream>>>(
      xr, xi, xb, 19 * 512, 27 * 512, 29 * 512, 32 * 512);

  (void)hipFuncSetAttribute((const void*)rgemm,
      hipFuncAttributeMaxDynamicSharedMemorySize, RG_LDS_BYTES);
  dim3 gB(DD / 256, NB / 256);   // (4, 64) = 256 blocks
  if (realOut) {
    rgemm<<<gB, dim3(512), RG_LDS_BYTES, stream>>>(xb, pack1, (float*)d_out, 1, 0);
  } else {
    rgemm<<<gB, dim3(512), RG_LDS_BYTES, stream>>>(xb, pack1, (float*)d_out, 2, 0);
    rgemm<<<gB, dim3(512), RG_LDS_BYTES, stream>>>(xb, pack2, (float*)d_out, 2, 1);
  }
}

// Round 13
// 281.908 us; speedup vs baseline: 1.0237x; 1.0237x over previous
//
#include <hip/hip_runtime.h>
#include <hip/hip_bf16.h>

#define DD 1024
#define NB 16384
#define SZ (DD * DD)
#define CHB 256

typedef unsigned short u16;
typedef __attribute__((ext_vector_type(2))) float f32x2;
typedef __attribute__((ext_vector_type(4))) float f32x4;
typedef __attribute__((ext_vector_type(8))) short short8;
typedef __attribute__((ext_vector_type(4))) short short4v;

__device__ __forceinline__ u16 f32_bf16(float f) {
  unsigned u = __builtin_bit_cast(unsigned, f);
  u += 0x7FFFu + ((u >> 16) & 1u);   // RNE
  return (u16)(u >> 16);
}
__device__ __forceinline__ float bf16_f32(u16 h) {
  unsigned u = ((unsigned)h) << 16;
  return __builtin_bit_cast(float, u);
}
__device__ __forceinline__ void gload16(const void* g, void* l) {
  __builtin_amdgcn_global_load_lds(
      (const __attribute__((address_space(1))) unsigned int*)g,
      (__attribute__((address_space(3))) unsigned int*)l, 16, 0, 0);
}

// ---------------------------------------------------------------- chain GEMM
// Complex bf16 GEMM, BM=64 BN=64 BK=32, 256 thr (4 waves 2x2).
// PAIRED-SLOT schedule with HOISTED READS (r10, 282us verified).  FROZEN:
// split-K (r6), 8-wave retile (r7), coop fusion (r8), 96KB counted ring
// (analysis) all regressed or null.  Structural optimum at 64KB LDS.
// Blocks >= CHB do f32->bf16 x-conversion into dead workspace planes.
struct CArgs {
  const u16 *Ar[3], *Ai[3];      // A planes [M][K]
  const u16 *Br[3], *Bi[3];      // B^T planes [N][K]
  int nseg;
  float alpha, g1, g2, ddiag;
  const u16 *e1r, *e1i, *e2r, *e2i;
  u16 *hi_n_re, *hi_n_im, *lo_n_re, *lo_n_im;   // normal outs (ld DD)
  u16 *t1_re, *t1_im;            // transposed hi outs
  u16 *t2_re, *t2_im;            // second transposed hi pair (packs)
  u16 *lt_re, *lt_im;            // transposed lo outs
  int t_ldt;                     // ld for transposed outs
  unsigned t1_xi;                // sign mask for t1 im (0x8000 => negate)
  const float *cxr, *cxi; u16 *cxb;
  int cm0a, cm1a, cm0b, cm1b;    // conversion row ranges
};

__global__ __launch_bounds__(256, 2) void zchain(CArgs g) {
  constexpr int SA = 64 * 32, SB = 64 * 32;      // u16 per plane
  constexpr int SLOT = 2 * SA + 2 * SB;          // 8192 u16 = 16 KB
  __shared__ __align__(16) u16 smem[4 * SLOT];   // 64 KB
  const int tid = threadIdx.x;

  if ((int)blockIdx.x >= CHB) {                  // -------- conversion blocks
    int nra = g.cm1a - g.cm0a;
    int tot = nra + (g.cm1b - g.cm0b);
    for (int r = (int)blockIdx.x - CHB; r < tot; r += 256) {
      int m = (r < nra) ? (g.cm0a + r) : (g.cm0b + r - nra);
      f32x4 v = ((const f32x4*)g.cxr)[m * 256 + tid];
      short4v s;
      #pragma unroll
      for (int e = 0; e < 4; ++e) s[e] = (short)f32_bf16(v[e]);
      ((short4v*)g.cxb)[m * 512 + tid] = s;
      f32x4 w = ((const f32x4*)g.cxi)[m * 256 + tid];
      #pragma unroll
      for (int e = 0; e < 4; ++e) s[e] = (short)f32_bf16(w[e]);
      ((short4v*)g.cxb)[m * 512 + 256 + tid] = s;
    }
    return;
  }

  const int lane = tid & 63, wave = tid >> 6;
  const int wr = wave >> 1, wc = wave & 1;
  const int l15 = lane & 15, lg = lane >> 4;

  // XCD swizzle: each XCD owns a 4x8 (by,bx) region of the 16x16 grid
  const int lin = blockIdx.x;
  const int xcd = lin & 7, tt = lin >> 3;        // tt in [0,32)
  const int by = (xcd >> 1) * 4 + (tt >> 3);
  const int bx = (xcd & 1) * 8 + (tt & 7);
  const int m0 = by * 64, n0 = bx * 64;

  // staging maps; granule swizzle q^((row>>1)&3) (conflict-free, matches
  // read-side slotR since (row>>1)&3 == (l15>>1)&3)
  const int arow = tid >> 2, agc = tid & 3;
  const int offA = (m0 + arow) * DD + ((agc ^ ((arow >> 1) & 3)) * 8);
  const int offB = (n0 + arow) * DD + ((agc ^ ((arow >> 1) & 3)) * 8);
  const int ldsAB = tid * 8;                     // lane-contiguous 16B

  const int slotR = lg ^ ((l15 >> 1) & 3);
  int frA[2], frB[2];
  #pragma unroll
  for (int mf = 0; mf < 2; ++mf)
    frA[mf] = (wr * 32 + mf * 16 + l15) * 32 + slotR * 8;
  #pragma unroll
  for (int nf = 0; nf < 2; ++nf)
    frB[nf] = (wc * 32 + nf * 16 + l15) * 32 + slotR * 8;

  const int nt = g.nseg * 32;                    // even (>=32)

  auto ISSUE = [&](int b) {
    if (b >= nt) return;
    int s = b >> 5, kk = (b & 31) << 5;
    u16* base = smem + (b & 3) * SLOT;
    gload16(g.Ar[s] + offA + kk, base + ldsAB);
    gload16(g.Ai[s] + offA + kk, base + SA + ldsAB);
    gload16(g.Br[s] + offB + kk, base + 2 * SA + ldsAB);
    gload16(g.Bi[s] + offB + kk, base + 2 * SA + SB + ldsAB);
  };

  f32x4 accre[2][2] = {};
  f32x4 accim[2][2] = {};

  // prologue: pair 0 only; expose latency once
  ISSUE(0); ISSUE(1);
  asm volatile("s_waitcnt vmcnt(0)" ::: "memory");
  __builtin_amdgcn_s_barrier();

  for (int b = 0; b < nt; b += 2) {
    // stage pair b+2 -> other half (consumed last iteration; barrier passed)
    ISSUE(b + 2); ISSUE(b + 3);

    // ---- hoisted reads: ALL 16 fragments of the pair upfront (both slots
    // resident; lets the compiler hide ds_read latency under first MFMAs)
    short8 ar[2][2], ai[2][2], br[2][2], bi[2][2];
    #pragma unroll
    for (int h2 = 0; h2 < 2; ++h2) {
      const u16* base = smem + ((b + h2) & 3) * SLOT;
      #pragma unroll
      for (int mf = 0; mf < 2; ++mf) {
        ar[h2][mf] = *(const short8*)(base + frA[mf]);
        ai[h2][mf] = *(const short8*)(base + SA + frA[mf]);
      }
      #pragma unroll
      for (int nf = 0; nf < 2; ++nf) {
        br[h2][nf] = *(const short8*)(base + 2 * SA + frB[nf]);
        bi[h2][nf] = *(const short8*)(base + 2 * SA + SB + frB[nf]);
      }
    }

    #pragma unroll
    for (int h2 = 0; h2 < 2; ++h2) {
      short8 bin[2];
      #pragma unroll
      for (int nf = 0; nf < 2; ++nf)
        #pragma unroll
        for (int e = 0; e < 8; ++e)
          bin[nf][e] = (short)(bi[h2][nf][e] ^ (short)0x8000);
      #pragma unroll
      for (int mf = 0; mf < 2; ++mf)
      #pragma unroll
      for (int nf = 0; nf < 2; ++nf) {
        accre[mf][nf] = __builtin_amdgcn_mfma_f32_16x16x32_bf16(ar[h2][mf], br[h2][nf],  accre[mf][nf], 0, 0, 0);
        accre[mf][nf] = __builtin_amdgcn_mfma_f32_16x16x32_bf16(ai[h2][mf], bin[nf],     accre[mf][nf], 0, 0, 0);
        accim[mf][nf] = __builtin_amdgcn_mfma_f32_16x16x32_bf16(ar[h2][mf], bi[h2][nf],  accim[mf][nf], 0, 0, 0);
        accim[mf][nf] = __builtin_amdgcn_mfma_f32_16x16x32_bf16(ai[h2][mf], br[h2][nf],  accim[mf][nf], 0, 0, 0);
      }
    }

    if (b + 2 < nt) {
      asm volatile("s_waitcnt vmcnt(0)" ::: "memory");   // pair b+2 landed
      __builtin_amdgcn_s_barrier();
    }
  }

  // ---- epilogue
  u16 hre[2][2][4], hie[2][2][4], lre[2][2][4], lie[2][2][4];
  #pragma unroll
  for (int mf = 0; mf < 2; ++mf)
  #pragma unroll
  for (int nf = 0; nf < 2; ++nf)
  #pragma unroll
  for (int r = 0; r < 4; ++r) {
    int gr = m0 + wr * 32 + mf * 16 + lg * 4 + r;
    int gc = n0 + wc * 32 + nf * 16 + l15;
    size_t idx = (size_t)gr * DD + gc;
    float v = g.alpha * accre[mf][nf][r];
    float w = g.alpha * accim[mf][nf][r];
    if (g.e1r) { v += g.g1 * bf16_f32(g.e1r[idx]); w += g.g1 * bf16_f32(g.e1i[idx]); }
    if (g.e2r) { v += g.g2 * bf16_f32(g.e2r[idx]); w += g.g2 * bf16_f32(g.e2i[idx]); }
    if (gr == gc) v += g.ddiag;
    u16 h1 = f32_bf16(v); hre[mf][nf][r] = h1;
    u16 h2 = f32_bf16(w); hie[mf][nf][r] = h2;
    lre[mf][nf][r] = f32_bf16(v - bf16_f32(h1));
    lie[mf][nf][r] = f32_bf16(w - bf16_f32(h2));
    if (g.hi_n_re) { g.hi_n_re[idx] = h1; g.hi_n_im[idx] = h2; }
    if (g.lo_n_re) { g.lo_n_re[idx] = lre[mf][nf][r]; g.lo_n_im[idx] = lie[mf][nf][r]; }
  }

  auto bounce = [&](u16 (&vals)[2][2][4], u16* outp, unsigned xorm) {
    if (!outp) return;
    __syncthreads();
    #pragma unroll
    for (int mf = 0; mf < 2; ++mf)
    #pragma unroll
    for (int nf = 0; nf < 2; ++nf)
    #pragma unroll
    for (int r = 0; r < 4; ++r) {
      int row = wr * 32 + mf * 16 + lg * 4 + r;
      int col = wc * 32 + nf * 16 + l15;
      smem[row * 66 + col] = vals[mf][nf][r];
    }
    __syncthreads();
    {
      int col = tid & 63, mb = (tid >> 6) * 16;
      short8 s0, s1;
      #pragma unroll
      for (int j = 0; j < 8; ++j) s0[j] = (short)(smem[(mb + j) * 66 + col] ^ xorm);
      #pragma unroll
      for (int j = 0; j < 8; ++j) s1[j] = (short)(smem[(mb + 8 + j) * 66 + col] ^ xorm);
      u16* p = outp + (size_t)(n0 + col) * g.t_ldt + m0 + mb;
      *(short8*)p = s0; *(short8*)(p + 8) = s1;
    }
  };

  bounce(hre, g.t1_re, 0);
  bounce(hie, g.t1_im, g.t1_xi);
  bounce(hre, g.t2_re, 0);
  bounce(hie, g.t2_im, 0);
  bounce(lre, g.lt_re, 0);
  bounce(lie, g.lt_im, 0);
}

// ---------------------------------------------------------------- big GEMM
// Real bf16 GEMM, 8-phase quadrant schedule, 16x16x32 MFMA (r10 verified).
// r11/r12 lesson (counter-backed): 32x32x16 frag reads (32 rows x 2 lanes)
// incur a shape-intrinsic ~6 cyc/read LDS conflict under BOTH granule
// swizzles tried — stay on 16x16x32 (16 rows x 4 lanes, 0 conflicts).
#define RG_SLOT2 (2 * 256 * 64)          // 32768 u16 = 64 KB per buffer
#define RG_LDS_BYTES (2 * RG_SLOT2 * 2)  // 128 KB
#define RG_TILES 32                      // K = 2048 / 64

__global__ __launch_bounds__(512, 2) void rgemm(
    const u16* __restrict__ A, const u16* __restrict__ B,
    float* __restrict__ out, int ostride, int ooff)
{
  extern __shared__ u16 smem[];
  const int tid = threadIdx.x, lane = tid & 63, wave = tid >> 6;
  const int wr = wave >> 2, wc = wave & 3;
  const int l15 = lane & 15, lg = lane >> 4;

  int bx, by;
  { int lin = blockIdx.y * gridDim.x + blockIdx.x;   // grid (4, 64) = 256
    int orig = (lin & 7) * 32 + (lin >> 3);
    bx = orig & 3; by = orig >> 2; }
  const int m0 = by * 256, n0 = bx * 256;

  const u16* __restrict__ Abase = A + (size_t)m0 * 2048;
  const u16* __restrict__ Bbase = B + (size_t)n0 * 2048;

  int gofsA[2], gofsB[2], lofs[2];
  #pragma unroll
  for (int i = 0; i < 2; ++i) {
    int c = i * 512 + tid;
    int sub = c >> 3;
    int sl = (c & 7) ^ (sub & 7);
    int rowA = (sub & 63) + 128 * (sub >> 6);
    int rowB = (sub & 31) + 64 * (sub >> 5);
    gofsA[i] = rowA * 2048 + sl * 8;
    gofsB[i] = rowB * 2048 + sl * 8;
    lofs[i] = c * 8;
  }

  int raf[8], rbf[8];   // [mf*2+k], [nf*2+k]
  #pragma unroll
  for (int mf = 0; mf < 4; ++mf)
    #pragma unroll
    for (int k = 0; k < 2; ++k)
      raf[mf * 2 + k] = (wr * 64 + mf * 16 + l15) * 64 +
                        (((k * 4 + lg) ^ (l15 & 7)) * 8);
  #pragma unroll
  for (int nf = 0; nf < 2; ++nf)
    #pragma unroll
    for (int k = 0; k < 2; ++k)
      rbf[nf * 2 + k] = (wc * 32 + nf * 16 + l15) * 64 +
                        (((k * 4 + lg) ^ (l15 & 7)) * 8);

  f32x4 acc[8][4] = {};
  short8 aA[8], bb[8];

#define MFMA_Q(mb, nb)                                                        \
  _Pragma("unroll")                                                           \
  for (int mf = 0; mf < 4; ++mf)                                              \
    _Pragma("unroll")                                                         \
    for (int nf = 0; nf < 2; ++nf)                                            \
      _Pragma("unroll")                                                       \
      for (int k = 0; k < 2; ++k)                                             \
        acc[(mb) + mf][(nb) + nf] = __builtin_amdgcn_mfma_f32_16x16x32_bf16(  \
            aA[mf * 2 + k], bb[((nb) + nf) * 2 + k], acc[(mb) + mf][(nb) + nf], 0, 0, 0);

  {
    gload16(Abase + gofsA[0], smem + lofs[0]);
    gload16(Abase + gofsA[1], smem + lofs[1]);
    gload16(Bbase + gofsB[0], smem + 16384 + lofs[0]);
    gload16(Bbase + gofsB[1], smem + 16384 + lofs[1]);
    gload16(Bbase + gofsB[0] + 32 * 2048, smem + 16384 + 8192 + lofs[0]);
    gload16(Bbase + gofsB[1] + 32 * 2048, smem + 16384 + 8192 + lofs[1]);
    gload16(Abase + gofsA[0] + 64 * 2048, smem + 8192 + lofs[0]);
    gload16(Abase + gofsA[1] + 64 * 2048, smem + 8192 + lofs[1]);
    gload16(Abase + gofsA[0] + 64, smem + RG_SLOT2 + lofs[0]);
    gload16(Abase + gofsA[1] + 64, smem + RG_SLOT2 + lofs[1]);
    gload16(Bbase + gofsB[0] + 64, smem + RG_SLOT2 + 16384 + lofs[0]);
    gload16(Bbase + gofsB[1] + 64, smem + RG_SLOT2 + 16384 + lofs[1]);
  }
  asm volatile("s_waitcnt vmcnt(4)" ::: "memory");
  __builtin_amdgcn_s_barrier();

  auto TILE = [&](int t, int gate, bool st01, bool st23) {
    const int b = t & 1;
    const u16* bA = smem + b * RG_SLOT2;
    const u16* bB = bA + 16384;
    u16* sOpp  = smem + (b ^ 1) * RG_SLOT2;
    u16* sSame = smem + b * RG_SLOT2;
    #pragma unroll
    for (int i = 0; i < 8; ++i) aA[i] = *(const short8*)(bA + raf[i]);
    #pragma unroll
    for (int i = 0; i < 4; ++i) bb[i] = *(const short8*)(bB + rbf[i]);
    if (st01) {
      int kk = (t + 1) * 64;
      gload16(Bbase + gofsB[0] + 32 * 2048 + kk, sOpp + 16384 + 8192 + lofs[0]);
      gload16(Bbase + gofsB[1] + 32 * 2048 + kk, sOpp + 16384 + 8192 + lofs[1]);
    }
    asm volatile("s_waitcnt lgkmcnt(8)" ::: "memory");
    __builtin_amdgcn_s_barrier();
    asm volatile("s_waitcnt lgkmcnt(0)" ::: "memory");
    __builtin_amdgcn_sched_barrier(0);
    __builtin_amdgcn_s_setprio(1);
    MFMA_Q(0, 0);
    __builtin_amdgcn_s_setprio(0);
    __builtin_amdgcn_s_barrier();
    #pragma unroll
    for (int i = 0; i < 4; ++i) bb[4 + i] = *(const short8*)(bB + 8192 + rbf[i]);
    if (st01) {
      int kk = (t + 1) * 64;
      gload16(Abase + gofsA[0] + 64 * 2048 + kk, sOpp + 8192 + lofs[0]);
      gload16(Abase + gofsA[1] + 64 * 2048 + kk, sOpp + 8192 + lofs[1]);
    }
    __builtin_amdgcn_s_barrier();
    asm volatile("s_waitcnt lgkmcnt(0)" ::: "memory");
    __builtin_amdgcn_sched_barrier(0);
    __builtin_amdgcn_s_setprio(1);
    MFMA_Q(0, 2);
    __builtin_amdgcn_s_setprio(0);
    __builtin_amdgcn_s_barrier();
    #pragma unroll
    for (int i = 0; i < 8; ++i) aA[i] = *(const short8*)(bA + 8192 + raf[i]);
    if (st23) {
      int kk = (t + 2) * 64;
      gload16(Abase + gofsA[0] + kk, sSame + lofs[0]);
      gload16(Abase + gofsA[1] + kk, sSame + lofs[1]);
    }
    __builtin_amdgcn_s_barrier();
    asm volatile("s_waitcnt lgkmcnt(0)" ::: "memory");
    __builtin_amdgcn_sched_barrier(0);
    __builtin_amdgcn_s_setprio(1);
    MFMA_Q(4, 0);
    __builtin_amdgcn_s_setprio(0);
    __builtin_amdgcn_s_barrier();
    if (st23) {
      int kk = (t + 2) * 64;
      gload16(Bbase + gofsB[0] + kk, sSame + 16384 + lofs[0]);
      gload16(Bbase + gofsB[1] + kk, sSame + 16384 + lofs[1]);
    }
    __builtin_amdgcn_s_barrier();
    __builtin_amdgcn_sched_barrier(0);
    __builtin_amdgcn_s_setprio(1);
    MFMA_Q(4, 2);
    __builtin_amdgcn_s_setprio(0);
    if (gate == 4)      asm volatile("s_waitcnt vmcnt(4)" ::: "memory");
    else if (gate == 0) asm volatile("s_waitcnt vmcnt(0)" ::: "memory");
    if (gate >= 0) __builtin_amdgcn_s_barrier();
  };

  for (int t = 0; t < RG_TILES - 2; ++t) TILE(t, 4, true, true);
  TILE(RG_TILES - 2, 0, true, false);
  TILE(RG_TILES - 1, -1, false, false);
#undef MFMA_Q

  #pragma unroll
  for (int mf = 0; mf < 8; ++mf)
  #pragma unroll
  for (int nf = 0; nf < 4; ++nf)
  #pragma unroll
  for (int r = 0; r < 4; ++r) {
    int gr = m0 + wr * 128 + mf * 16 + lg * 4 + r;
    int gc = n0 + wc * 64 + nf * 16 + l15;
    out[((size_t)gr * DD + gc) * ostride + ooff] = acc[mf][nf][r];
  }
}

// ---------------------------------------------------------------- prep
__global__ __launch_bounds__(256) void prep_w(
    const float* __restrict__ wre, const float* __restrict__ wim,
    u16* Shr, u16* Shi_, u16* Slr, u16* Sli, u16* Snr)
{
  __shared__ float tr[32][33], ti[32][33];
  const int tx = threadIdx.x, ty = threadIdx.y;
  const int bx = blockIdx.x, by = blockIdx.y;
  #pragma unroll
  for (int k = 0; k < 4; ++k) {
    int r = bx * 32 + ty + 8 * k, c = by * 32 + tx;
    tr[ty + 8 * k][tx] = wre[r * DD + c];
    ti[ty + 8 * k][tx] = wim[r * DD + c];
  }
  __syncthreads();
  #pragma unroll
  for (int k = 0; k < 4; ++k) {
    int i = by * 32 + ty + 8 * k, j = bx * 32 + tx;
    float wr_ij = wre[i * DD + j], wi_ij = wim[i * DD + j];
    float wr_ji = tr[tx][ty + 8 * k], wi_ji = ti[tx][ty + 8 * k];
    float Sre = wr_ji - wr_ij;
    float Sim = wi_ij + wi_ji;
    int idx = i * DD + j;
    u16 h1 = f32_bf16(Sre); Shr[idx] = h1; Slr[idx] = f32_bf16(Sre - bf16_f32(h1));
    u16 h2 = f32_bf16(Sim); Shi_[idx] = h2; Sli[idx] = f32_bf16(Sim - bf16_f32(h2));
    Snr[idx] = (u16)(h1 ^ 0x8000u);
  }
}

__global__ __launch_bounds__(256) void prep_x2(
    const float* __restrict__ xr, const float* __restrict__ xi,
    u16* __restrict__ xb, int m0a, int m1a, int m0b, int m1b)
{
  int nra = m1a - m0a;
  int tot = nra + (m1b - m0b);
  const int tid = threadIdx.x;
  for (int r = blockIdx.x; r < tot; r += gridDim.x) {
    int m = (r < nra) ? (m0a + r) : (m0b + r - nra);
    f32x4 v = ((const f32x4*)xr)[m * 256 + tid];
    short4v s;
    #pragma unroll
    for (int e = 0; e < 4; ++e) s[e] = (short)f32_bf16(v[e]);
    ((short4v*)xb)[m * 512 + tid] = s;
    f32x4 w = ((const f32x4*)xi)[m * 256 + tid];
    #pragma unroll
    for (int e = 0; e < 4; ++e) s[e] = (short)f32_bf16(w[e]);
    ((short4v*)xb)[m * 512 + 256 + tid] = s;
  }
}

// ---------------------------------------------------------------- launcher
extern "C" void kernel_launch(void* const* d_in, const int* in_sizes, int n_in,
                              void* d_out, int out_size, void* d_ws, size_t ws_size,
                              hipStream_t stream)
{
  const float* xr  = (const float*)d_in[0];
  const float* xi  = (const float*)d_in[1];
  const float* wre = (const float*)d_in[2];
  const float* wim = (const float*)d_in[3];
  const bool realOut = (out_size == NB * DD);

  u16* P0 = (u16*)d_ws;
  auto PL = [&](int k) { return P0 + (size_t)k * SZ; };
  // plane map (peak 35 planes real path; 37 in complex fallback):
  u16 *Shr = PL(0), *Shi_ = PL(1), *Slr = PL(2), *Sli = PL(3), *Snr = PL(4);
  u16 *Cn_r = PL(5), *Cn_i = PL(6), *Ct_r = PL(7), *Ct_i = PL(8);
  u16 *Rn_r = PL(9), *Rn_i = PL(10);
  u16 *XA_hn_r = PL(11), *XA_hn_i = PL(12), *XA_ht_r = PL(13), *XA_ht_i = PL(14);
  u16 *XB_hn_r = PL(19), *XB_hn_i = PL(20), *XB_ht_r = PL(21), *XB_ht_i = PL(22);
  u16 *XB_ln_r = PL(23), *XB_ln_i = PL(24), *XB_lt_r = PL(25), *XB_lt_i = PL(26);
  u16 *T_ht_r = PL(29), *T_ht_i = PL(30), *T_lt_r = PL(31), *T_lt_i = PL(32);
  u16 *pack1 = PL(33);           // [1024][2048]
  u16 *pack2 = PL(35);           // complex path
  u16 *xb    = PL(0);            // [16384][2048] bf16, planes 0-31

  dim3 blk(256);
  prep_w<<<dim3(32, 32), dim3(32, 8), 0, stream>>>(
      wre, wim, Shr, Shi_, Slr, Sli, Snr);

  auto chain = [&](CArgs& a, int p0, int p1, int p0b, int p1b) {
    a.cxr = xr; a.cxi = xi; a.cxb = xb;
    a.cm0a = p0 * 512; a.cm1a = p1 * 512;
    a.cm0b = p0b * 512; a.cm1b = p1b * 512;
    zchain<<<dim3(CHB + 256), blk, 0, stream>>>(a);
  };
  auto base = [&]() { CArgs a{}; a.nseg = 1; a.t_ldt = DD; return a; };

  // deg-3 Chebyshev seed on s = 1+lambda^2 in [1, 7.8] (rho0 = 0.2089):
  //   R = 0.7910964 I + 0.2381155 C + 0.0212604 C^2,  C = S^2
  // G1: C = S*S
  { CArgs a = base();
    a.Ar[0] = Shr; a.Ai[0] = Shi_; a.Br[0] = Snr; a.Bi[0] = Shi_;
    a.alpha = 1.f;
    a.hi_n_re = Cn_r; a.hi_n_im = Cn_i; a.t1_re = Ct_r; a.t1_im = Ct_i;
    chain(a, 15, 19, 0, 0); }
  // G2: R = q2*(C*C) + q1*C + q0*I
  { CArgs a = base();
    a.Ar[0] = Cn_r; a.Ai[0] = Cn_i; a.Br[0] = Ct_r; a.Bi[0] = Ct_i;
    a.alpha = 0.0212604f; a.g1 = 0.2381155f; a.e1r = Cn_r; a.e1i = Cn_i;
    a.ddiag = 0.7910964f;
    a.hi_n_re = Rn_r; a.hi_n_im = Rn_i;
    chain(a, 27, 29, 0, 0); }
  // G3: X0 = R*S + R
  { CArgs a = base();
    a.Ar[0] = Rn_r; a.Ai[0] = Rn_i; a.Br[0] = Snr; a.Bi[0] = Shi_;
    a.alpha = 1.f; a.g1 = 1.f; a.e1r = Rn_r; a.e1i = Rn_i;
    a.hi_n_re = XA_hn_r; a.hi_n_im = XA_hn_i; a.t1_re = XA_ht_r; a.t1_im = XA_ht_i;
    chain(a, 0, 0, 0, 0); }
  // quadratic NS: T = X0 - S*X0  (transposed out only)
  { CArgs a = base();
    a.Ar[0] = Shr; a.Ai[0] = Shi_; a.Br[0] = XA_ht_r; a.Bi[0] = XA_ht_i;
    a.alpha = -1.f; a.g1 = 1.f; a.e1r = XA_hn_r; a.e1i = XA_hn_i;
    a.t1_re = T_ht_r; a.t1_im = T_ht_i;
    chain(a, 4, 8, 0, 0); }
  // X1 = 2*X0 - X0*T   (hi+lo, normal+transposed)
  { CArgs a = base();
    a.Ar[0] = XA_hn_r; a.Ai[0] = XA_hn_i; a.Br[0] = T_ht_r; a.Bi[0] = T_ht_i;
    a.alpha = -1.f; a.g1 = 2.f; a.e1r = XA_hn_r; a.e1i = XA_hn_i;
    a.hi_n_re = XB_hn_r; a.hi_n_im = XB_hn_i; a.t1_re = XB_ht_r; a.t1_im = XB_ht_i;
    a.lo_n_re = XB_ln_r; a.lo_n_im = XB_ln_i; a.lt_re = XB_lt_r; a.lt_im = XB_lt_i;
    chain(a, 8, 11, 0, 0); }
  // polish-1 (split): T' = X - S*X,  S*X ~ Sh*Xh + Sh*Xl + Sl*Xh
  { CArgs a = base();
    a.nseg = 3;
    a.Ar[0] = Shr; a.Ai[0] = Shi_; a.Br[0] = XB_ht_r; a.Bi[0] = XB_ht_i;
    a.Ar[1] = Shr; a.Ai[1] = Shi_; a.Br[1] = XB_lt_r; a.Bi[1] = XB_lt_i;
    a.Ar[2] = Slr; a.Ai[2] = Sli;  a.Br[2] = XB_ht_r; a.Bi[2] = XB_ht_i;
    a.alpha = -1.f;
    a.g1 = 1.f; a.e1r = XB_hn_r; a.e1i = XB_hn_i;
    a.g2 = 1.f; a.e2r = XB_ln_r; a.e2i = XB_ln_i;
    a.t1_re = T_ht_r; a.t1_im = T_ht_i; a.lt_re = T_lt_r; a.lt_im = T_lt_i;
    chain(a, 11, 15, 0, 0); }
  // polish-2 + H-fold: H = -2(Xh*T'h + Xh*T'l) + 4Xh + 2Xl - I  (= U^T)
  // pack1 = [Hr^T | -Hi^T]; pack2 = [Hi^T | Hr^T] (complex path)
  { CArgs a = base();
    a.nseg = 2;
    a.Ar[0] = XB_hn_r; a.Ai[0] = XB_hn_i; a.Br[0] = T_ht_r; a.Bi[0] = T_ht_i;
    a.Ar[1] = XB_hn_r; a.Ai[1] = XB_hn_i; a.Br[1] = T_lt_r; a.Bi[1] = T_lt_i;
    a.alpha = -2.f;
    a.g1 = 4.f; a.e1r = XB_hn_r; a.e1i = XB_hn_i;
    a.g2 = 2.f; a.e2r = XB_ln_r; a.e2i = XB_ln_i;
    a.ddiag = -1.f;
    a.t_ldt = 2048;
    a.t1_re = pack1; a.t1_im = pack1 + 1024; a.t1_xi = 0x8000u;
    if (!realOut) { a.t2_im = pack2; a.t2_re = pack2 + 1024; }
    chain(a, 0, 4, 0, 0); }

  // remaining xb planes: [19,27) and [29,32)
  prep_x2<<<dim3(1024), blk, 0, stream>>>(
      xr, xi, xb, 19 * 512, 27 * 512, 29 * 512, 32 * 512);

  (void)hipFuncSetAttribute((const void*)rgemm,
      hipFuncAttributeMaxDynamicSharedMemorySize, RG_LDS_BYTES);
  dim3 gB(DD / 256, NB / 256);   // (4, 64) = 256 blocks
  if (realOut) {
    rgemm<<<gB, dim3(512), RG_LDS_BYTES, stream>>>(xb, pack1, (float*)d_out, 1, 0);
  } else {
    rgemm<<<gB, dim3(512), RG_LDS_BYTES, stream>>>(xb, pack1, (float*)d_out, 2, 0);
    rgemm<<<gB, dim3(512), RG_LDS_BYTES, stream>>>(xb, pack2, (float*)d_out, 2, 1);
  }
}